// Round 1
// baseline (1339.352 us; speedup 1.0000x reference)
//
#include <hip/hip_runtime.h>
#include <math.h>

#define B_    2048
#define T_    8
#define CIN_  2048
#define CH_   1024
#define M_    32
#define NCLS_ 21
#define NM_   (NCLS_*M_)   // 672
#define EPS_  1e-8f

// ---------------------------------------------------------------------------
// Kernel E: Ek[n,o,m] = sum_c WEk[o,c]*sf[n,c,m] + bEk[o]   (layout n,o,m)
//           EvT[n,m,o] = sum_c WEv[o,c]*sf[n,c,m] + bEv[o]  (layout n,m,o)
// grid (21, CH/8), block (32,8): x=m, y=o-sub
// ---------------------------------------------------------------------------
__global__ __launch_bounds__(256) void kE(
    const float* __restrict__ sf, const float* __restrict__ WEk,
    const float* __restrict__ bEk, const float* __restrict__ WEv,
    const float* __restrict__ bEv, float* __restrict__ Ek,
    float* __restrict__ EvT)
{
  const int n = blockIdx.x;
  const int o = blockIdx.y * 8 + threadIdx.y;
  const int m = threadIdx.x;
  const float* sfp = sf + (size_t)n * CIN_ * M_ + m;
  const float* wkp = WEk + (size_t)o * CIN_;
  const float* wvp = WEv + (size_t)o * CIN_;
  float ak = 0.f, av = 0.f;
  for (int c = 0; c < CIN_; ++c) {
    float s = sfp[(size_t)c * M_];
    ak += wkp[c] * s;
    av += wvp[c] * s;
  }
  Ek [(size_t)n * CH_ * M_ + (size_t)o * M_ + m] = ak + bEk[o];
  EvT[((size_t)n * M_ + m) * CH_ + o]            = av + bEv[o];
}

// ---------------------------------------------------------------------------
// Normalize Ek over o (axis=1) in place -> Ekn. grid 21, block (32,8)
// ---------------------------------------------------------------------------
__global__ __launch_bounds__(256) void kNormEk(float* __restrict__ Ek)
{
  const int n = blockIdx.x;
  const int m = threadIdx.x;   // 0..31
  const int oy = threadIdx.y;  // 0..7
  float ss = 0.f;
  for (int o = oy; o < CH_; o += 8) {
    float v = Ek[(size_t)n * CH_ * M_ + (size_t)o * M_ + m];
    ss += v * v;
  }
  __shared__ float part[8][32];
  part[oy][m] = ss;
  __syncthreads();
  __shared__ float invs[32];
  if (oy == 0) {
    float t = 0.f;
    for (int j = 0; j < 8; ++j) t += part[j][m];
    invs[m] = 1.f / fmaxf(sqrtf(t), EPS_);
  }
  __syncthreads();
  const float inv = invs[m];
  for (int o = oy; o < CH_; o += 8) {
    Ek[(size_t)n * CH_ * M_ + (size_t)o * M_ + m] *= inv;
  }
}

// ---------------------------------------------------------------------------
// EvW[nm] = sum_o EvT[nm*CH+o] * Ww[o].  grid 672, block 64 (one wave)
// ---------------------------------------------------------------------------
__global__ __launch_bounds__(64) void kEvW(
    const float* __restrict__ EvT, const float* __restrict__ Ww,
    float* __restrict__ EvW)
{
  const int nm = blockIdx.x;
  const int lane = threadIdx.x;
  float s = 0.f;
  for (int o = lane; o < CH_; o += 64)
    s += EvT[(size_t)nm * CH_ + o] * Ww[o];
  for (int off = 32; off; off >>= 1) s += __shfl_xor(s, off);
  if (lane == 0) EvW[nm] = s;
}

// ---------------------------------------------------------------------------
// kv GEMM: kv[b, o2] = xl[b,:] . W[o2,:] + bias[o2], o2<1024 -> Wk, else Wv
// xl[b,c] = x[b*T*CIN + (T-1)*CIN + c].  64x64 tile, K-tile 16, 256 thr, 4x4.
// ---------------------------------------------------------------------------
__global__ __launch_bounds__(256) void gemm_kv(
    const float* __restrict__ x, const float* __restrict__ Wk,
    const float* __restrict__ bk, const float* __restrict__ Wv,
    const float* __restrict__ bv, float* __restrict__ kv)
{
  __shared__ float As[16][65];
  __shared__ float Bs[16][65];
  const int tid = threadIdx.x;
  const int tx = tid & 15, ty = tid >> 4;
  const int b0 = blockIdx.y * 64, o0 = blockIdx.x * 64;
  const float* W    = (o0 < CH_) ? Wk : Wv;
  const float* bias = (o0 < CH_) ? bk : bv;
  const int orow0   = (o0 < CH_) ? o0 : o0 - CH_;
  const int lr = tid >> 2;          // 0..63
  const int lc = (tid & 3) * 4;     // 0,4,8,12
  float acc[4][4] = {};
  for (int k0 = 0; k0 < CIN_; k0 += 16) {
    const float* ap = x + (size_t)(b0 + lr) * (T_ * CIN_) + (T_ - 1) * CIN_ + k0 + lc;
    float4 a4 = *(const float4*)ap;
    As[lc + 0][lr] = a4.x; As[lc + 1][lr] = a4.y;
    As[lc + 2][lr] = a4.z; As[lc + 3][lr] = a4.w;
    const float* bp = W + (size_t)(orow0 + lr) * CIN_ + k0 + lc;
    float4 b4 = *(const float4*)bp;
    Bs[lc + 0][lr] = b4.x; Bs[lc + 1][lr] = b4.y;
    Bs[lc + 2][lr] = b4.z; Bs[lc + 3][lr] = b4.w;
    __syncthreads();
    for (int kk = 0; kk < 16; ++kk) {
      float a[4], b[4];
      #pragma unroll
      for (int i = 0; i < 4; ++i) a[i] = As[kk][ty * 4 + i];
      #pragma unroll
      for (int j = 0; j < 4; ++j) b[j] = Bs[kk][tx * 4 + j];
      #pragma unroll
      for (int i = 0; i < 4; ++i)
        #pragma unroll
        for (int j = 0; j < 4; ++j) acc[i][j] += a[i] * b[j];
    }
    __syncthreads();
  }
  #pragma unroll
  for (int i = 0; i < 4; ++i) {
    const int r = b0 + ty * 4 + i;
    #pragma unroll
    for (int j = 0; j < 4; ++j) {
      const int c = o0 + tx * 4 + j;
      kv[(size_t)r * (2 * CH_) + c] = acc[i][j] + bias[orow0 + tx * 4 + j];
    }
  }
}

// ---------------------------------------------------------------------------
// Normalize k rows (first CH_ cols of kv) in place. grid B, block 64
// ---------------------------------------------------------------------------
__global__ __launch_bounds__(64) void kNormK(float* __restrict__ kv)
{
  const int b = blockIdx.x;
  const int lane = threadIdx.x;
  float ss = 0.f;
  for (int o = lane; o < CH_; o += 64) {
    float v = kv[(size_t)b * (2 * CH_) + o];
    ss += v * v;
  }
  for (int off = 32; off; off >>= 1) ss += __shfl_xor(ss, off);
  const float inv = 1.f / fmaxf(sqrtf(ss), EPS_);
  for (int o = lane; o < CH_; o += 64)
    kv[(size_t)b * (2 * CH_) + o] *= inv;
}

// ---------------------------------------------------------------------------
// cos GEMM: cosb[b, nm] = sum_o kn[b,o] * Ekn[n,o,m], nm=n*32+m
// ---------------------------------------------------------------------------
__global__ __launch_bounds__(256) void gemm_cos(
    const float* __restrict__ kv, const float* __restrict__ Ekn,
    float* __restrict__ cosb)
{
  __shared__ float As[16][65];
  __shared__ float Bs[16][65];
  const int tid = threadIdx.x;
  const int tx = tid & 15, ty = tid >> 4;
  const int b0 = blockIdx.y * 64, nm0 = blockIdx.x * 64;
  const int lr = tid >> 2;
  const int lc = (tid & 3) * 4;
  float acc[4][4] = {};
  for (int k0 = 0; k0 < CH_; k0 += 16) {
    const float* ap = kv + (size_t)(b0 + lr) * (2 * CH_) + k0 + lc;
    float4 a4 = *(const float4*)ap;
    As[lc + 0][lr] = a4.x; As[lc + 1][lr] = a4.y;
    As[lc + 2][lr] = a4.z; As[lc + 3][lr] = a4.w;
    const int nm = nm0 + lr;
    float bv0 = 0.f, bv1 = 0.f, bv2 = 0.f, bv3 = 0.f;
    if (nm < NM_) {
      const int n = nm >> 5, m = nm & 31;
      const float* bp = Ekn + (size_t)n * CH_ * M_ + (size_t)(k0 + lc) * M_ + m;
      bv0 = bp[0]; bv1 = bp[M_]; bv2 = bp[2 * M_]; bv3 = bp[3 * M_];
    }
    Bs[lc + 0][lr] = bv0; Bs[lc + 1][lr] = bv1;
    Bs[lc + 2][lr] = bv2; Bs[lc + 3][lr] = bv3;
    __syncthreads();
    for (int kk = 0; kk < 16; ++kk) {
      float a[4], b[4];
      #pragma unroll
      for (int i = 0; i < 4; ++i) a[i] = As[kk][ty * 4 + i];
      #pragma unroll
      for (int j = 0; j < 4; ++j) b[j] = Bs[kk][tx * 4 + j];
      #pragma unroll
      for (int i = 0; i < 4; ++i)
        #pragma unroll
        for (int j = 0; j < 4; ++j) acc[i][j] += a[i] * b[j];
    }
    __syncthreads();
  }
  #pragma unroll
  for (int i = 0; i < 4; ++i) {
    const int r = b0 + ty * 4 + i;
    #pragma unroll
    for (int j = 0; j < 4; ++j) {
      const int c = nm0 + tx * 4 + j;
      if (c < NM_) cosb[(size_t)r * NM_ + c] = acc[i][j];
    }
  }
}

// ---------------------------------------------------------------------------
// Softmax chain per b: w = softmax_m(cos); logit[n] = sum_m w*EvW + bw;
// fw = softmax_n(logit); ww[n,m] = fw[n]*w[n,m].  In-place cosb -> ww.
// grid B, block 256
// ---------------------------------------------------------------------------
__global__ __launch_bounds__(256) void kSoftmax(
    float* __restrict__ cosb, const float* __restrict__ EvW,
    const float* __restrict__ bw)
{
  const int b = blockIdx.x;
  const int tid = threadIdx.x;
  __shared__ float sc[NM_];
  __shared__ float sl[NCLS_];
  for (int i = tid; i < NM_; i += 256) sc[i] = cosb[(size_t)b * NM_ + i];
  __syncthreads();
  if (tid < NCLS_) {
    const int base = tid * M_;
    float mx = -1e30f;
    for (int m = 0; m < M_; ++m) mx = fmaxf(mx, sc[base + m]);
    float s = 0.f;
    for (int m = 0; m < M_; ++m) {
      float e = __expf(sc[base + m] - mx);
      sc[base + m] = e;
      s += e;
    }
    const float inv = 1.f / s;
    float lg = 0.f;
    for (int m = 0; m < M_; ++m) {
      float w = sc[base + m] * inv;
      sc[base + m] = w;
      lg += w * EvW[base + m];
    }
    sl[tid] = lg + bw[0];
  }
  __syncthreads();
  if (tid == 0) {
    float mx = -1e30f;
    for (int n = 0; n < NCLS_; ++n) mx = fmaxf(mx, sl[n]);
    float s = 0.f;
    for (int n = 0; n < NCLS_; ++n) { float e = __expf(sl[n] - mx); sl[n] = e; s += e; }
    const float inv = 1.f / s;
    for (int n = 0; n < NCLS_; ++n) sl[n] *= inv;
  }
  __syncthreads();
  for (int i = tid; i < NM_; i += 256)
    cosb[(size_t)b * NM_ + i] = sc[i] * sl[i >> 5];
}

// ---------------------------------------------------------------------------
// fE GEMM: fE[b,o] = sum_nm ww[b,nm] * EvT[nm*CH + o].  K = 672 = 42*16.
// ---------------------------------------------------------------------------
__global__ __launch_bounds__(256) void gemm_fe(
    const float* __restrict__ ww, const float* __restrict__ EvT,
    float* __restrict__ fE)
{
  __shared__ float As[16][65];
  __shared__ float Bs[16][65];
  const int tid = threadIdx.x;
  const int tx = tid & 15, ty = tid >> 4;
  const int b0 = blockIdx.y * 64, o0 = blockIdx.x * 64;
  const int lr = tid >> 2;          // A loader row 0..63
  const int lc = (tid & 3) * 4;     // A loader col
  const int bkk = tid >> 4;         // B loader k 0..15
  const int boo = (tid & 15) * 4;   // B loader col 0..60
  float acc[4][4] = {};
  for (int k0 = 0; k0 < NM_; k0 += 16) {
    const float* ap = ww + (size_t)(b0 + lr) * NM_ + k0 + lc;
    float4 a4 = *(const float4*)ap;
    As[lc + 0][lr] = a4.x; As[lc + 1][lr] = a4.y;
    As[lc + 2][lr] = a4.z; As[lc + 3][lr] = a4.w;
    const float* bp = EvT + (size_t)(k0 + bkk) * CH_ + o0 + boo;
    float4 b4 = *(const float4*)bp;
    Bs[bkk][boo + 0] = b4.x; Bs[bkk][boo + 1] = b4.y;
    Bs[bkk][boo + 2] = b4.z; Bs[bkk][boo + 3] = b4.w;
    __syncthreads();
    for (int kk = 0; kk < 16; ++kk) {
      float a[4], b[4];
      #pragma unroll
      for (int i = 0; i < 4; ++i) a[i] = As[kk][ty * 4 + i];
      #pragma unroll
      for (int j = 0; j < 4; ++j) b[j] = Bs[kk][tx * 4 + j];
      #pragma unroll
      for (int i = 0; i < 4; ++i)
        #pragma unroll
        for (int j = 0; j < 4; ++j) acc[i][j] += a[i] * b[j];
    }
    __syncthreads();
  }
  #pragma unroll
  for (int i = 0; i < 4; ++i) {
    const int r = b0 + ty * 4 + i;
    #pragma unroll
    for (int j = 0; j < 4; ++j) {
      const int c = o0 + tx * 4 + j;
      fE[(size_t)r * CH_ + c] = acc[i][j];
    }
  }
}

// ---------------------------------------------------------------------------
// Final: out[b,n] = bout[n] + sum_j relu(h[b,j]) * Wout[n,j]
// h = [v(=kv[:,1024:2048]), fE].  grid B, block 256 (4 waves)
// ---------------------------------------------------------------------------
__global__ __launch_bounds__(256) void kOut(
    const float* __restrict__ kv, const float* __restrict__ fE,
    const float* __restrict__ Wout, const float* __restrict__ bout,
    float* __restrict__ out)
{
  const int b = blockIdx.x;
  const int tid = threadIdx.x;
  __shared__ float h[2 * CH_];
  for (int j = tid; j < CH_; j += 256)
    h[j] = fmaxf(kv[(size_t)b * (2 * CH_) + CH_ + j], 0.f);
  for (int j = tid; j < CH_; j += 256)
    h[CH_ + j] = fmaxf(fE[(size_t)b * CH_ + j], 0.f);
  __syncthreads();
  const int wave = tid >> 6, lane = tid & 63;
  for (int n = wave; n < NCLS_; n += 4) {
    const float* wr = Wout + (size_t)n * (2 * CH_);
    float s = 0.f;
    for (int j = lane; j < 2 * CH_; j += 64) s += h[j] * wr[j];
    for (int off = 32; off; off >>= 1) s += __shfl_xor(s, off);
    if (lane == 0) out[(size_t)b * NCLS_ + n] = s + bout[n];
  }
}

// ---------------------------------------------------------------------------
extern "C" void kernel_launch(void* const* d_in, const int* in_sizes, int n_in,
                              void* d_out, int out_size, void* d_ws, size_t ws_size,
                              hipStream_t stream)
{
  const float* x    = (const float*)d_in[0];
  const float* sf   = (const float*)d_in[1];
  const float* Wk   = (const float*)d_in[2];
  const float* bk   = (const float*)d_in[3];
  const float* Wv   = (const float*)d_in[4];
  const float* bv   = (const float*)d_in[5];
  const float* WEk  = (const float*)d_in[6];
  const float* bEk  = (const float*)d_in[7];
  const float* WEv  = (const float*)d_in[8];
  const float* bEv  = (const float*)d_in[9];
  const float* Ww   = (const float*)d_in[10];
  const float* bw   = (const float*)d_in[11];
  const float* Wout = (const float*)d_in[12];
  const float* bout = (const float*)d_in[13];
  float* out = (float*)d_out;

  float* ws = (float*)d_ws;
  float* kv   = ws;                              // B * 2CH      = 4,194,304
  float* Ek   = kv   + (size_t)B_ * 2 * CH_;     // NCLS*CH*M    =   688,128
  float* EvT  = Ek   + (size_t)NCLS_ * CH_ * M_; // NCLS*M*CH    =   688,128
  float* EvW  = EvT  + (size_t)NCLS_ * M_ * CH_; // NM           =       672
  float* cosb = EvW  + NM_;                      // B * NM       = 1,376,256
  float* fE   = cosb + (size_t)B_ * NM_;         // B * CH       = 2,097,152

  kE<<<dim3(NCLS_, CH_ / 8), dim3(32, 8), 0, stream>>>(sf, WEk, bEk, WEv, bEv, Ek, EvT);
  kNormEk<<<NCLS_, dim3(32, 8), 0, stream>>>(Ek);
  kEvW<<<NM_, 64, 0, stream>>>(EvT, Ww, EvW);
  gemm_kv<<<dim3(32, 32), 256, 0, stream>>>(x, Wk, bk, Wv, bv, kv);
  kNormK<<<B_, 64, 0, stream>>>(kv);
  gemm_cos<<<dim3(11, 32), 256, 0, stream>>>(kv, Ek, cosb);
  kSoftmax<<<B_, 256, 0, stream>>>(cosb, EvW, bw);
  gemm_fe<<<dim3(CH_ / 64, B_ / 64), 256, 0, stream>>>(cosb, EvT, fE);
  kOut<<<B_, 256, 0, stream>>>(kv, fE, Wout, bout, out);
}

// Round 2
// 510.289 us; speedup vs baseline: 2.6247x; 2.6247x over previous
//
#include <hip/hip_runtime.h>
#include <math.h>

#define B_    2048
#define T_    8
#define CIN_  2048
#define CH_   1024
#define M_    32
#define NCLS_ 21
#define NM_   (NCLS_*M_)   // 672
#define NMP_  768          // nm padded to 6*128
#define EPS_  1e-8f

typedef __bf16 bf16_t;
typedef bf16_t bf16x4 __attribute__((ext_vector_type(4)));
typedef bf16_t bf16x8 __attribute__((ext_vector_type(8)));
typedef float  floatx4 __attribute__((ext_vector_type(4)));

#define BK_  64
#define LDT_ 72   // LDS row stride (bf16 elems): 64 + 8 pad -> 2-way-max bank conflicts

// ---------------------------------------------------------------------------
// Generic 128x128 bf16 MFMA GEMM:  C[M][N] = A[M][K] . B^T + bias
//   A row-major [M][K] stride lda (f32, converted to bf16 at staging)
//   B given as rows over n, K-contiguous, stride ldb. n < nsplit -> B0[n],
//   else B1[n-nsplit]. bias0/bias1 may be null. Rows >= mzero are written 0.
// Requires: M%128==0 (padded), N%128==0, K%64==0, nsplit%128==0.
// grid (N/128, M/128), block 256 (4 waves, each wave does 64x64 = 4x4 frags).
// ---------------------------------------------------------------------------
__global__ __launch_bounds__(256) void gemm_bf16(
    const float* __restrict__ A, int lda,
    const float* __restrict__ B0, const float* __restrict__ B1,
    int ldb, int nsplit,
    const float* __restrict__ bias0, const float* __restrict__ bias1,
    float* __restrict__ C, int ldc, int mzero, int K)
{
  __shared__ bf16_t As[128 * LDT_];
  __shared__ bf16_t Bs[128 * LDT_];
  const int tid = threadIdx.x;
  const int n0 = blockIdx.x * 128, m0 = blockIdx.y * 128;

  const float* Bp; const float* biasp; int nb, coff;
  if (n0 < nsplit) { Bp = B0; biasp = bias0; nb = n0;          coff = 0;      }
  else             { Bp = B1; biasp = bias1; nb = n0 - nsplit; coff = nsplit; }

  const int wv = tid >> 6, lane = tid & 63;
  const int wm = (wv >> 1) * 64, wn = (wv & 1) * 64;
  const int l15 = lane & 15, quad = lane >> 4;

  floatx4 acc[4][4] = {};

  for (int k0 = 0; k0 < K; k0 += BK_) {
    __syncthreads();
    // stage A and B tiles (f32 -> bf16), 8 float4 each per thread
    #pragma unroll
    for (int q = 0; q < 8; ++q) {
      const int flat = q * 256 + tid;
      const int row = flat >> 4;            // 0..127
      const int k4  = (flat & 15) * 4;      // 0,4,...,60
      float4 a4 = *(const float4*)(A + (size_t)(m0 + row) * lda + k0 + k4);
      bf16x4 av = { (bf16_t)a4.x, (bf16_t)a4.y, (bf16_t)a4.z, (bf16_t)a4.w };
      *(bf16x4*)(&As[row * LDT_ + k4]) = av;
      float4 b4 = *(const float4*)(Bp + (size_t)(nb + row) * ldb + k0 + k4);
      bf16x4 bv = { (bf16_t)b4.x, (bf16_t)b4.y, (bf16_t)b4.z, (bf16_t)b4.w };
      *(bf16x4*)(&Bs[row * LDT_ + k4]) = bv;
    }
    __syncthreads();
    // compute: 2 k-steps of 32, 4x4 fragments per wave
    #pragma unroll
    for (int ks = 0; ks < 2; ++ks) {
      bf16x8 af[4], bfr[4];
      #pragma unroll
      for (int i = 0; i < 4; ++i)
        af[i] = *(const bf16x8*)(&As[(wm + i * 16 + l15) * LDT_ + ks * 32 + quad * 8]);
      #pragma unroll
      for (int j = 0; j < 4; ++j)
        bfr[j] = *(const bf16x8*)(&Bs[(wn + j * 16 + l15) * LDT_ + ks * 32 + quad * 8]);
      #pragma unroll
      for (int i = 0; i < 4; ++i)
        #pragma unroll
        for (int j = 0; j < 4; ++j)
          acc[i][j] = __builtin_amdgcn_mfma_f32_16x16x32_bf16(af[i], bfr[j], acc[i][j], 0, 0, 0);
    }
  }

  // epilogue: C/D layout col = lane&15, row = quad*4 + reg (m89-verified)
  #pragma unroll
  for (int i = 0; i < 4; ++i) {
    const int rbase = m0 + wm + i * 16 + quad * 4;
    #pragma unroll
    for (int j = 0; j < 4; ++j) {
      const int c = n0 + wn + j * 16 + l15;
      float badd = 0.f;
      if (biasp) badd = biasp[c - coff];
      #pragma unroll
      for (int r = 0; r < 4; ++r) {
        const int rr = rbase + r;
        float v = acc[i][j][r] + badd;
        if (rr >= mzero) v = 0.f;
        C[(size_t)rr * ldc + c] = v;
      }
    }
  }
}

// ---------------------------------------------------------------------------
// sf[n][c][m] -> sfT[n*32+m][c], rows 672..767 zeroed. grid (24, 64), 256 thr
// ---------------------------------------------------------------------------
__global__ __launch_bounds__(256) void kTrSf(
    const float* __restrict__ sf, float* __restrict__ sfT)
{
  __shared__ float t[32][33];
  const int nn = blockIdx.x;        // 0..23
  const int c0 = blockIdx.y * 32;
  const int tid = threadIdx.x;
  const int cc = tid & 31, r8 = tid >> 5;
  #pragma unroll
  for (int q = 0; q < 4; ++q) {
    const int cl = r8 + q * 8;  // c_local
    float v = 0.f;
    if (nn < NCLS_) v = sf[((size_t)nn * CIN_ + c0 + cl) * M_ + cc];
    t[cl][cc] = v;
  }
  __syncthreads();
  #pragma unroll
  for (int q = 0; q < 4; ++q) {
    const int ml = r8 + q * 8;  // m_local
    sfT[(size_t)(nn * 32 + ml) * CIN_ + c0 + cc] = t[cc][ml];
  }
}

// ---------------------------------------------------------------------------
// Per nm-row: normalize Ek half (cols 0..1023) of E2 in place; EvW[nm] =
// dot(Ev half, Ww). grid 672, block 64 (one wave)
// ---------------------------------------------------------------------------
__global__ __launch_bounds__(64) void kNormE(
    float* __restrict__ E2, const float* __restrict__ Ww, float* __restrict__ EvW)
{
  const int nm = blockIdx.x;
  float* row = E2 + (size_t)nm * 2048;
  const int lane = threadIdx.x;
  float ss = 0.f;
  for (int o = lane; o < CH_; o += 64) { const float v = row[o]; ss += v * v; }
  for (int off = 32; off; off >>= 1) ss += __shfl_xor(ss, off);
  const float inv = 1.f / fmaxf(sqrtf(ss), EPS_);
  for (int o = lane; o < CH_; o += 64) row[o] *= inv;
  float dd = 0.f;
  for (int o = lane; o < CH_; o += 64) dd += row[CH_ + o] * Ww[o];
  for (int off = 32; off; off >>= 1) dd += __shfl_xor(dd, off);
  if (lane == 0) EvW[nm] = dd;
}

// ---------------------------------------------------------------------------
// Normalize k rows (first CH_ cols of kv) in place. grid B, block 64
// ---------------------------------------------------------------------------
__global__ __launch_bounds__(64) void kNormK(float* __restrict__ kv)
{
  const int b = blockIdx.x;
  const int lane = threadIdx.x;
  float ss = 0.f;
  for (int o = lane; o < CH_; o += 64) {
    const float v = kv[(size_t)b * (2 * CH_) + o];
    ss += v * v;
  }
  for (int off = 32; off; off >>= 1) ss += __shfl_xor(ss, off);
  const float inv = 1.f / fmaxf(sqrtf(ss), EPS_);
  for (int o = lane; o < CH_; o += 64)
    kv[(size_t)b * (2 * CH_) + o] *= inv;
}

// ---------------------------------------------------------------------------
// Ev2[o][nm] = E2[nm][1024+o]. grid (NMP/32=24, CH/32=32), 256 thr.
// (E2 pad rows are zero -> Ev2 pad cols zero.)
// ---------------------------------------------------------------------------
__global__ __launch_bounds__(256) void kTrEv(
    const float* __restrict__ E2, float* __restrict__ Ev2)
{
  __shared__ float t[32][33];
  const int nm0 = blockIdx.x * 32;
  const int o0 = blockIdx.y * 32;
  const int tid = threadIdx.x;
  const int cc = tid & 31, r8 = tid >> 5;
  #pragma unroll
  for (int q = 0; q < 4; ++q) {
    const int r = r8 + q * 8;
    t[r][cc] = E2[(size_t)(nm0 + r) * 2048 + CH_ + o0 + cc];
  }
  __syncthreads();
  #pragma unroll
  for (int q = 0; q < 4; ++q) {
    const int r = r8 + q * 8;
    Ev2[(size_t)(o0 + r) * NMP_ + nm0 + cc] = t[cc][r];
  }
}

// ---------------------------------------------------------------------------
// Softmax chain per b (ld = NMP_): w = softmax_m(cos); logit[n] = w.EvW + bw;
// fw = softmax_n(logit); ww[nm] = fw[n]*w[n,m]; pad cols zeroed. In place.
// ---------------------------------------------------------------------------
__global__ __launch_bounds__(256) void kSoftmax(
    float* __restrict__ cosb, const float* __restrict__ EvW,
    const float* __restrict__ bw)
{
  const int b = blockIdx.x;
  const int tid = threadIdx.x;
  __shared__ float sc[NM_];
  __shared__ float sl[NCLS_];
  for (int i = tid; i < NM_; i += 256) sc[i] = cosb[(size_t)b * NMP_ + i];
  __syncthreads();
  if (tid < NCLS_) {
    const int base = tid * M_;
    float mx = -1e30f;
    for (int m = 0; m < M_; ++m) mx = fmaxf(mx, sc[base + m]);
    float s = 0.f;
    for (int m = 0; m < M_; ++m) {
      const float e = __expf(sc[base + m] - mx);
      sc[base + m] = e;
      s += e;
    }
    const float inv = 1.f / s;
    float lg = 0.f;
    for (int m = 0; m < M_; ++m) {
      const float w = sc[base + m] * inv;
      sc[base + m] = w;
      lg += w * EvW[base + m];
    }
    sl[tid] = lg + bw[0];
  }
  __syncthreads();
  if (tid == 0) {
    float mx = -1e30f;
    for (int n = 0; n < NCLS_; ++n) mx = fmaxf(mx, sl[n]);
    float s = 0.f;
    for (int n = 0; n < NCLS_; ++n) { const float e = __expf(sl[n] - mx); sl[n] = e; s += e; }
    const float inv = 1.f / s;
    for (int n = 0; n < NCLS_; ++n) sl[n] *= inv;
  }
  __syncthreads();
  for (int i = tid; i < NMP_; i += 256) {
    const float v = (i < NM_) ? sc[i] * sl[i >> 5] : 0.f;
    cosb[(size_t)b * NMP_ + i] = v;
  }
}

// ---------------------------------------------------------------------------
// out[b,n] = bout[n] + sum_j relu(h[j]) * Wout[n,j];  h = [v, fE]
// ---------------------------------------------------------------------------
__global__ __launch_bounds__(256) void kOut(
    const float* __restrict__ kv, const float* __restrict__ fE,
    const float* __restrict__ Wout, const float* __restrict__ bout,
    float* __restrict__ out)
{
  const int b = blockIdx.x;
  const int tid = threadIdx.x;
  __shared__ float h[2 * CH_];
  for (int j = tid; j < CH_; j += 256)
    h[j] = fmaxf(kv[(size_t)b * (2 * CH_) + CH_ + j], 0.f);
  for (int j = tid; j < CH_; j += 256)
    h[CH_ + j] = fmaxf(fE[(size_t)b * CH_ + j], 0.f);
  __syncthreads();
  const int wave = tid >> 6, lane = tid & 63;
  for (int n = wave; n < NCLS_; n += 4) {
    const float* wr = Wout + (size_t)n * (2 * CH_);
    float s = 0.f;
    for (int j = lane; j < 2 * CH_; j += 64) s += h[j] * wr[j];
    for (int off = 32; off; off >>= 1) s += __shfl_xor(s, off);
    if (lane == 0) out[(size_t)b * NCLS_ + n] = s + bout[n];
  }
}

// ---------------------------------------------------------------------------
extern "C" void kernel_launch(void* const* d_in, const int* in_sizes, int n_in,
                              void* d_out, int out_size, void* d_ws, size_t ws_size,
                              hipStream_t stream)
{
  const float* x    = (const float*)d_in[0];
  const float* sf   = (const float*)d_in[1];
  const float* Wk   = (const float*)d_in[2];
  const float* bk   = (const float*)d_in[3];
  const float* Wv   = (const float*)d_in[4];
  const float* bv   = (const float*)d_in[5];
  const float* WEk  = (const float*)d_in[6];
  const float* bEk  = (const float*)d_in[7];
  const float* WEv  = (const float*)d_in[8];
  const float* bEv  = (const float*)d_in[9];
  const float* Ww   = (const float*)d_in[10];
  const float* bw   = (const float*)d_in[11];
  const float* Wout = (const float*)d_in[12];
  const float* bout = (const float*)d_in[13];
  float* out = (float*)d_out;

  float* ws = (float*)d_ws;
  float* kv     = ws;                                 // 2048*2048 = 4,194,304
  float* sfT_fE = kv + (size_t)B_ * 2 * CH_;          // max(768*2048, 2048*1024) = 2,097,152
  float* E2     = sfT_fE + (size_t)B_ * CH_;          // 768*2048   = 1,572,864
  float* Ev2    = E2 + (size_t)NMP_ * 2 * CH_;        // 1024*768   =   786,432
  float* EvW    = Ev2 + (size_t)CH_ * NMP_;           // 768
  float* cosb   = EvW + NMP_;                         // 2048*768   = 1,572,864
  float* sfT = sfT_fE;   // sfT dead after E2 GEMM; fE reuses the space
  float* fE  = sfT_fE;

  // 1) sf -> sfT[nm][c] (pad rows zero)
  kTrSf<<<dim3(24, CIN_ / 32), 256, 0, stream>>>(sf, sfT);
  // 2) kv[b][o2] = xl . [Wk;Wv]^T + bias       M=2048 N=2048 K=2048
  gemm_bf16<<<dim3(16, 16), 256, 0, stream>>>(
      x + (T_ - 1) * CIN_, T_ * CIN_, Wk, Wv, CIN_, CH_, bk, bv,
      kv, 2 * CH_, B_, CIN_);
  // 3) E2[nm][o2] = sfT . [WEk;WEv]^T + bias   M=768 N=2048 K=2048, rows>=672 -> 0
  gemm_bf16<<<dim3(16, 6), 256, 0, stream>>>(
      sfT, CIN_, WEk, WEv, CIN_, CH_, bEk, bEv,
      E2, 2 * CH_, NM_, CIN_);
  // 4) normalize Ek rows in place + EvW
  kNormE<<<NM_, 64, 0, stream>>>(E2, Ww, EvW);
  // 5) normalize k rows in place
  kNormK<<<B_, 64, 0, stream>>>(kv);
  // 6) Ev2[o][nm] = E2[nm][1024+o]
  kTrEv<<<dim3(NMP_ / 32, CH_ / 32), 256, 0, stream>>>(E2, Ev2);
  // 7) cosb[b][nm] = kn . Ekn^T                M=2048 N=768 K=1024
  gemm_bf16<<<dim3(6, 16), 256, 0, stream>>>(
      kv, 2 * CH_, E2, E2, 2 * CH_, NMP_, nullptr, nullptr,
      cosb, NMP_, B_, CH_);
  // 8) softmax chain -> ww (in place in cosb, pads zeroed)
  kSoftmax<<<B_, 256, 0, stream>>>(cosb, EvW, bw);
  // 9) fE[b][o] = ww . Ev2^T                   M=2048 N=1024 K=768
  gemm_bf16<<<dim3(8, 16), 256, 0, stream>>>(
      cosb, NMP_, Ev2, Ev2, NMP_, CH_, nullptr, nullptr,
      fE, CH_, B_, NMP_);
  // 10) output
  kOut<<<B_, 256, 0, stream>>>(kv, fE, Wout, bout, out);
}

// Round 3
// 400.221 us; speedup vs baseline: 3.3465x; 1.2750x over previous
//
#include <hip/hip_runtime.h>
#include <math.h>

#define B_    2048
#define T_    8
#define CIN_  2048
#define CH_   1024
#define M_    32
#define NCLS_ 21
#define NM_   (NCLS_*M_)   // 672
#define NMP_  768          // nm padded to 6*128
#define EPS_  1e-8f

typedef __bf16 bf16_t;
typedef bf16_t bf16x4 __attribute__((ext_vector_type(4)));
typedef bf16_t bf16x8 __attribute__((ext_vector_type(8)));
typedef float  floatx4 __attribute__((ext_vector_type(4)));

#define GLOBAL_AS __attribute__((address_space(1)))
#define LDS_AS    __attribute__((address_space(3)))

// ---------------------------------------------------------------------------
// 128x128 bf16 MFMA GEMM (m97 structure):  C[M][N] = A . B^T + bias
//   A,B bf16, K-contiguous rows, shared leading dim `ld`. Staging via
//   global_load_lds dwordx4 with XOR-swizzled k-blocks (conflict-free b128
//   frag reads). m0 >= msplit switches to the (A1,B1,bias1) operand set
//   (used to fuse the kv and E GEMMs into one dispatch).
//   Rows >= mzero are written as 0. bias may be null; indexed by absolute col.
// grid (N/128, M/128), block 256.
// ---------------------------------------------------------------------------
__global__ __launch_bounds__(256) void gemm_bf16(
    const bf16_t* __restrict__ A0, const bf16_t* __restrict__ A1, int msplit,
    const bf16_t* __restrict__ B0, const bf16_t* __restrict__ B1,
    const float* __restrict__ bias0, const float* __restrict__ bias1,
    int ld, float* __restrict__ C, int ldc, int mzero, int K)
{
  __shared__ bf16_t As[128 * 64];
  __shared__ bf16_t Bs[128 * 64];
  const int tid = threadIdx.x;
  const int n0 = blockIdx.x * 128, m0 = blockIdx.y * 128;

  const bf16_t* A; const bf16_t* B; const float* bias; int mrow;
  if (m0 < msplit) { A = A0; B = B0; bias = bias0; mrow = m0; }
  else             { A = A1; B = B1; bias = bias1; mrow = m0 - msplit; }

  const int w = tid >> 6, lane = tid & 63;
  // staging: instr q of wave w covers tile rows w*32+q*8 .. +7.
  // lane l -> row srow=l/8, k-block (l%8) XOR srow (swizzle folded into the
  // GLOBAL address; LDS dest stays uniform-base + lane*16 as HW requires).
  const int srow = lane >> 3;
  const int sblk = (lane & 7) ^ srow;
  const bf16_t* ga = A + (size_t)(mrow + w * 32 + srow) * ld + sblk * 8;
  const bf16_t* gb = B + (size_t)(n0   + w * 32 + srow) * ld + sblk * 8;

  const int wm = (w >> 1) * 64, wn = (w & 1) * 64;
  const int l15 = lane & 15, quad = lane >> 4;
  const int sx = l15 & 7;  // frag-read xor key = row&7

  floatx4 acc[4][4] = {};

  for (int k0 = 0; k0 < K; k0 += 64) {
    __syncthreads();
    #pragma unroll
    for (int q = 0; q < 4; ++q) {
      __builtin_amdgcn_global_load_lds(
          (const GLOBAL_AS void*)(ga + (size_t)q * 8 * ld),
          (LDS_AS void*)(&As[(w * 4 + q) * 512]), 16, 0, 0);
      __builtin_amdgcn_global_load_lds(
          (const GLOBAL_AS void*)(gb + (size_t)q * 8 * ld),
          (LDS_AS void*)(&Bs[(w * 4 + q) * 512]), 16, 0, 0);
    }
    ga += 64; gb += 64;
    __syncthreads();
    #pragma unroll
    for (int ks = 0; ks < 2; ++ks) {
      bf16x8 af[4], bfr[4];
      #pragma unroll
      for (int i = 0; i < 4; ++i)
        af[i] = *(const bf16x8*)(&As[(wm + i * 16 + l15) * 64 + ((ks * 4 + quad) ^ sx) * 8]);
      #pragma unroll
      for (int j = 0; j < 4; ++j)
        bfr[j] = *(const bf16x8*)(&Bs[(wn + j * 16 + l15) * 64 + ((ks * 4 + quad) ^ sx) * 8]);
      #pragma unroll
      for (int i = 0; i < 4; ++i)
        #pragma unroll
        for (int j = 0; j < 4; ++j)
          acc[i][j] = __builtin_amdgcn_mfma_f32_16x16x32_bf16(af[i], bfr[j], acc[i][j], 0, 0, 0);
    }
  }

  // epilogue: C/D layout col = lane&15, row = quad*4 + reg (m89-verified)
  #pragma unroll
  for (int i = 0; i < 4; ++i) {
    const int rbase = m0 + wm + i * 16 + quad * 4;
    #pragma unroll
    for (int j = 0; j < 4; ++j) {
      const int c = n0 + wn + j * 16 + l15;
      const float badd = bias ? bias[c] : 0.f;
      #pragma unroll
      for (int r = 0; r < 4; ++r) {
        const int rr = rbase + r;
        float v = acc[i][j][r] + badd;
        if (rr >= mzero) v = 0.f;
        C[(size_t)rr * ldc + c] = v;
      }
    }
  }
}

// ---------------------------------------------------------------------------
// Prep: f32 -> bf16 conversions of x (last timestep), [Wk;Wv], [WEk;WEv];
// concat biases to f32 bkv/bE. grid 3073 x 256.
// ---------------------------------------------------------------------------
__global__ __launch_bounds__(256) void kPrep(
    const float* __restrict__ x, const float* __restrict__ Wk,
    const float* __restrict__ Wv, const float* __restrict__ WEk,
    const float* __restrict__ WEv, const float* __restrict__ bk,
    const float* __restrict__ bv, const float* __restrict__ bEk,
    const float* __restrict__ bEv,
    bf16_t* __restrict__ xb, bf16_t* __restrict__ Wkvb, bf16_t* __restrict__ WEb,
    float* __restrict__ bkv, float* __restrict__ bE)
{
  const int blk = blockIdx.x;
  if (blk >= 3072) {
    for (int i = threadIdx.x; i < CH_; i += 256) {
      bkv[i] = bk[i]; bkv[CH_ + i] = bv[i];
      bE[i]  = bEk[i]; bE[CH_ + i] = bEv[i];
    }
    return;
  }
  const int sec = blk >> 10;
  const int t = ((blk & 1023) << 8) + threadIdx.x;  // 0..262143
  const size_t e0 = (size_t)t * 16;
  const int row = (int)(e0 >> 11);
  const int col = (int)(e0 & 2047);
  const float* src;
  bf16_t* dst;
  if (sec == 0) {
    src = x + (size_t)row * (T_ * CIN_) + (size_t)(T_ - 1) * CIN_ + col;
    dst = xb + e0;
  } else if (sec == 1) {
    src = (row < CH_ ? Wk + (size_t)row * CIN_ : Wv + (size_t)(row - CH_) * CIN_) + col;
    dst = Wkvb + e0;
  } else {
    src = (row < CH_ ? WEk + (size_t)row * CIN_ : WEv + (size_t)(row - CH_) * CIN_) + col;
    dst = WEb + e0;
  }
  #pragma unroll
  for (int q = 0; q < 4; ++q) {
    const float4 v = *(const float4*)(src + q * 4);
    bf16x4 o = { (bf16_t)v.x, (bf16_t)v.y, (bf16_t)v.z, (bf16_t)v.w };
    *(bf16x4*)(dst + q * 4) = o;
  }
}

// ---------------------------------------------------------------------------
// sf[n][c][m] -> sfTb[n*32+m][c] (bf16), rows 672..767 zero. grid (24,64)x256
// ---------------------------------------------------------------------------
__global__ __launch_bounds__(256) void kTrSf(
    const float* __restrict__ sf, bf16_t* __restrict__ sfTb)
{
  __shared__ float t[32][33];
  const int nn = blockIdx.x;
  const int c0 = blockIdx.y * 32;
  const int tid = threadIdx.x;
  const int cc = tid & 31, r8 = tid >> 5;
  #pragma unroll
  for (int q = 0; q < 4; ++q) {
    const int cl = r8 + q * 8;
    float v = 0.f;
    if (nn < NCLS_) v = sf[((size_t)nn * CIN_ + c0 + cl) * M_ + cc];
    t[cl][cc] = v;
  }
  __syncthreads();
  #pragma unroll
  for (int q = 0; q < 4; ++q) {
    const int ml = r8 + q * 8;
    sfTb[(size_t)(nn * 32 + ml) * CIN_ + c0 + cc] = (bf16_t)t[cc][ml];
  }
}

// ---------------------------------------------------------------------------
// Row-normalize first 1024 cols of KVE row r:
//   r < 2048  -> knb[r] (bf16)
//   r >= 2048 -> Eknb[r-2048] (bf16) + EvW[r-2048] = dot(cols 1024.., Ww)
// KVE unmodified. grid 2816, block 64.
// ---------------------------------------------------------------------------
__global__ __launch_bounds__(64) void kNormKE(
    const float* __restrict__ KVE, const float* __restrict__ Ww,
    bf16_t* __restrict__ knb, bf16_t* __restrict__ Eknb, float* __restrict__ EvW)
{
  const int r = blockIdx.x;
  const int lane = threadIdx.x;
  const float* row = KVE + (size_t)r * 2048;
  float ss = 0.f;
  for (int o = lane; o < CH_; o += 64) { const float v = row[o]; ss += v * v; }
  for (int off = 32; off; off >>= 1) ss += __shfl_xor(ss, off);
  const float inv = 1.f / fmaxf(sqrtf(ss), EPS_);
  bf16_t* dst = (r < B_) ? knb + (size_t)r * CH_ : Eknb + (size_t)(r - B_) * CH_;
  for (int o = lane; o < CH_; o += 64) dst[o] = (bf16_t)(row[o] * inv);
  if (r >= B_) {
    float dd = 0.f;
    for (int o = lane; o < CH_; o += 64) dd += row[CH_ + o] * Ww[o];
    for (int off = 32; off; off >>= 1) dd += __shfl_xor(dd, off);
    if (lane == 0) EvW[r - B_] = dd;
  }
}

// ---------------------------------------------------------------------------
// Ev2b[o][nm] = KVE[2048+nm][1024+o] (bf16). grid (24,32) x 256
// ---------------------------------------------------------------------------
__global__ __launch_bounds__(256) void kTrEv(
    const float* __restrict__ KVE, bf16_t* __restrict__ Ev2b)
{
  __shared__ float t[32][33];
  const int nm0 = blockIdx.x * 32;
  const int o0 = blockIdx.y * 32;
  const int tid = threadIdx.x;
  const int cc = tid & 31, r8 = tid >> 5;
  #pragma unroll
  for (int q = 0; q < 4; ++q) {
    const int r = r8 + q * 8;
    t[r][cc] = KVE[(size_t)(B_ + nm0 + r) * 2048 + CH_ + o0 + cc];
  }
  __syncthreads();
  #pragma unroll
  for (int q = 0; q < 4; ++q) {
    const int r = r8 + q * 8;
    Ev2b[(size_t)(o0 + r) * NMP_ + nm0 + cc] = (bf16_t)t[cc][r];
  }
}

// ---------------------------------------------------------------------------
// Softmax chain per b: w = softmax_m(cos); logit[n] = w.EvW + bw;
// fw = softmax_n(logit); wwb[nm] = fw[n]*w[n,m] (bf16, pads zero).
// ---------------------------------------------------------------------------
__global__ __launch_bounds__(256) void kSoftmax(
    const float* __restrict__ cosb, const float* __restrict__ EvW,
    const float* __restrict__ bw, bf16_t* __restrict__ wwb)
{
  const int b = blockIdx.x;
  const int tid = threadIdx.x;
  __shared__ float sc[NM_];
  __shared__ float sl[NCLS_];
  for (int i = tid; i < NM_; i += 256) sc[i] = cosb[(size_t)b * NMP_ + i];
  __syncthreads();
  if (tid < NCLS_) {
    const int base = tid * M_;
    float mx = -1e30f;
    for (int m = 0; m < M_; ++m) mx = fmaxf(mx, sc[base + m]);
    float s = 0.f;
    for (int m = 0; m < M_; ++m) {
      const float e = __expf(sc[base + m] - mx);
      sc[base + m] = e;
      s += e;
    }
    const float inv = 1.f / s;
    float lg = 0.f;
    for (int m = 0; m < M_; ++m) {
      const float w = sc[base + m] * inv;
      sc[base + m] = w;
      lg += w * EvW[base + m];
    }
    sl[tid] = lg + bw[0];
  }
  __syncthreads();
  if (tid == 0) {
    float mx = -1e30f;
    for (int n = 0; n < NCLS_; ++n) mx = fmaxf(mx, sl[n]);
    float s = 0.f;
    for (int n = 0; n < NCLS_; ++n) { const float e = __expf(sl[n] - mx); sl[n] = e; s += e; }
    const float inv = 1.f / s;
    for (int n = 0; n < NCLS_; ++n) sl[n] *= inv;
  }
  __syncthreads();
  for (int i = tid; i < NMP_; i += 256) {
    const float v = (i < NM_) ? sc[i] * sl[i >> 5] : 0.f;
    wwb[(size_t)b * NMP_ + i] = (bf16_t)v;
  }
}

// ---------------------------------------------------------------------------
// out[b,n] = bout[n] + sum_j relu(h[j]) * Wout[n,j];  h = [v, fE]
// v = KVE[b][1024..2047]. grid B, block 256.
// ---------------------------------------------------------------------------
__global__ __launch_bounds__(256) void kOut(
    const float* __restrict__ KVE, const float* __restrict__ fE,
    const float* __restrict__ Wout, const float* __restrict__ bout,
    float* __restrict__ out)
{
  const int b = blockIdx.x;
  const int tid = threadIdx.x;
  __shared__ float h[2 * CH_];
  for (int j = tid; j < CH_; j += 256)
    h[j] = fmaxf(KVE[(size_t)b * 2048 + CH_ + j], 0.f);
  for (int j = tid; j < CH_; j += 256)
    h[CH_ + j] = fmaxf(fE[(size_t)b * CH_ + j], 0.f);
  __syncthreads();
  const int wave = tid >> 6, lane = tid & 63;
  for (int n = wave; n < NCLS_; n += 4) {
    const float* wr = Wout + (size_t)n * (2 * CH_);
    float s = 0.f;
    for (int j = lane; j < 2 * CH_; j += 64) s += h[j] * wr[j];
    for (int off = 32; off; off >>= 1) s += __shfl_xor(s, off);
    if (lane == 0) out[(size_t)b * NCLS_ + n] = s + bout[n];
  }
}

// ---------------------------------------------------------------------------
extern "C" void kernel_launch(void* const* d_in, const int* in_sizes, int n_in,
                              void* d_out, int out_size, void* d_ws, size_t ws_size,
                              hipStream_t stream)
{
  const float* x    = (const float*)d_in[0];
  const float* sf   = (const float*)d_in[1];
  const float* Wk   = (const float*)d_in[2];
  const float* bk   = (const float*)d_in[3];
  const float* Wv   = (const float*)d_in[4];
  const float* bv   = (const float*)d_in[5];
  const float* WEk  = (const float*)d_in[6];
  const float* bEk  = (const float*)d_in[7];
  const float* WEv  = (const float*)d_in[8];
  const float* bEv  = (const float*)d_in[9];
  const float* Ww   = (const float*)d_in[10];
  const float* bw   = (const float*)d_in[11];
  const float* Wout = (const float*)d_in[12];
  const float* bout = (const float*)d_in[13];
  float* out = (float*)d_out;

  char* ws = (char*)d_ws;
  // persistent region
  float*  KVE  = (float*)ws;                               // 2816*2048 f32 = 23,068,672 B
  char*   RA   = ws + 23068672;                            // overlay region (28,311,552 B)
  // phase A (until fused GEMM done)
  bf16_t* xb   = (bf16_t*)(RA);                            //  8,388,608
  bf16_t* Wkvb = (bf16_t*)(RA + 8388608);                  //  8,388,608
  bf16_t* WEb  = (bf16_t*)(RA + 16777216);                 //  8,388,608
  bf16_t* sfTb = (bf16_t*)(RA + 25165824);                 //  3,145,728
  // phase B (overlays xb/Wkvb/WEb — all dead after the fused GEMM)
  bf16_t* knb  = (bf16_t*)(RA);                            //  4,194,304
  bf16_t* Eknb = (bf16_t*)(RA + 4194304);                  //  1,572,864
  bf16_t* Ev2b = (bf16_t*)(RA + 5767168);                  //  1,572,864
  bf16_t* wwb  = (bf16_t*)(RA + 7340032);                  //  3,145,728
  float*  cosb = (float*)(RA + 10485760);                  //  6,291,456
  float*  fE   = (float*)(RA + 16777216);                  //  8,388,608
  // small persistents
  char*   SM   = ws + 23068672 + 28311552;
  float*  bkv  = (float*)(SM);                             //  8,192
  float*  bE   = (float*)(SM + 8192);                      //  8,192
  float*  EvW  = (float*)(SM + 16384);                     //  3,072

  // 1) convert weights/x to bf16, concat biases
  kPrep<<<3073, 256, 0, stream>>>(x, Wk, Wv, WEk, WEv, bk, bv, bEk, bEv,
                                  xb, Wkvb, WEb, bkv, bE);
  // 2) sf -> sfTb (bf16, pad rows zero)
  kTrSf<<<dim3(24, CIN_ / 32), 256, 0, stream>>>(sf, sfTb);
  // 3) fused GEMM: rows 0..2047: kv = xb.[Wk;Wv]^T + bkv
  //                rows 2048..2815: E2 = sfTb.[WEk;WEv]^T + bE (rows>=2720 -> 0)
  gemm_bf16<<<dim3(16, 22), 256, 0, stream>>>(
      xb, sfTb, B_, Wkvb, WEb, bkv, bE, CIN_, KVE, 2048, B_ + NM_, CIN_);
  // 4) normalize k rows -> knb, Ek rows -> Eknb, EvW
  kNormKE<<<B_ + NMP_, 64, 0, stream>>>(KVE, Ww, knb, Eknb, EvW);
  // 5) Ev transpose -> Ev2b
  kTrEv<<<dim3(NMP_ / 32, CH_ / 32), 256, 0, stream>>>(KVE, Ev2b);
  // 6) cos GEMM: cosb[b][nm] = knb . Eknb^T   M=2048 N=768 K=1024
  gemm_bf16<<<dim3(6, 16), 256, 0, stream>>>(
      knb, knb, 1 << 30, Eknb, Eknb, nullptr, nullptr, CH_, cosb, NMP_, B_, CH_);
  // 7) softmax chain -> wwb (bf16, pads zero)
  kSoftmax<<<B_, 256, 0, stream>>>(cosb, EvW, bw, wwb);
  // 8) fE GEMM: fE[b][o] = wwb . Ev2b^T       M=2048 N=1024 K=768
  gemm_bf16<<<dim3(8, 16), 256, 0, stream>>>(
      wwb, wwb, 1 << 30, Ev2b, Ev2b, nullptr, nullptr, NMP_, fE, CH_, B_, NMP_);
  // 9) output
  kOut<<<B_, 256, 0, stream>>>(KVE, fE, Wout, bout, out);
}

// Round 4
// 358.691 us; speedup vs baseline: 3.7340x; 1.1158x over previous
//
#include <hip/hip_runtime.h>
#include <math.h>

#define B_    2048
#define T_    8
#define CIN_  2048
#define CH_   1024
#define M_    32
#define NCLS_ 21
#define NM_   (NCLS_*M_)   // 672
#define NMP_  768          // nm padded to 6*128
#define EPS_  1e-8f

typedef __bf16 bf16_t;
typedef bf16_t bf16x4 __attribute__((ext_vector_type(4)));
typedef bf16_t bf16x8 __attribute__((ext_vector_type(8)));
typedef float  floatx4 __attribute__((ext_vector_type(4)));

#define GLOBAL_AS __attribute__((address_space(1)))
#define LDS_AS    __attribute__((address_space(3)))

// ---------------------------------------------------------------------------
// 128x128 bf16 MFMA GEMM, split-K over blockIdx.z:
//   C[z][M][N] partial = A[.,zK..zK+Ksplit) . B^T (+ bias if z==0)
//   m0 >= msplit switches operand set (A1,B1,bias1). Rows >= mzero -> 0.
//   Consumers sum the z-planes.
// ---------------------------------------------------------------------------
__global__ __launch_bounds__(256) void gemm128(
    const bf16_t* __restrict__ A0, const bf16_t* __restrict__ A1, int msplit,
    const bf16_t* __restrict__ B0, const bf16_t* __restrict__ B1,
    const float* __restrict__ bias0, const float* __restrict__ bias1,
    int ld, float* __restrict__ C, int ldc, size_t strideC, int mzero, int Ksplit)
{
  __shared__ bf16_t As[128 * 64];
  __shared__ bf16_t Bs[128 * 64];
  const int tid = threadIdx.x;
  const int n0 = blockIdx.x * 128, m0 = blockIdx.y * 128;
  const int z = blockIdx.z;

  const bf16_t* A; const bf16_t* B; const float* bias; int mrow;
  if (m0 < msplit) { A = A0; B = B0; bias = bias0; mrow = m0; }
  else             { A = A1; B = B1; bias = bias1; mrow = m0 - msplit; }
  const int koff = z * Ksplit;

  const int w = tid >> 6, lane = tid & 63;
  const int srow = lane >> 3;
  const int sblk = (lane & 7) ^ srow;   // xor-swizzle folded into global addr
  const bf16_t* ga = A + (size_t)(mrow + w * 32 + srow) * ld + koff + sblk * 8;
  const bf16_t* gb = B + (size_t)(n0   + w * 32 + srow) * ld + koff + sblk * 8;

  const int wm = (w >> 1) * 64, wn = (w & 1) * 64;
  const int l15 = lane & 15, quad = lane >> 4;
  const int sx = l15 & 7;

  floatx4 acc[4][4] = {};

  for (int k0 = 0; k0 < Ksplit; k0 += 64) {
    __syncthreads();
    #pragma unroll
    for (int q = 0; q < 4; ++q) {
      __builtin_amdgcn_global_load_lds(
          (const GLOBAL_AS void*)(ga + (size_t)q * 8 * ld),
          (LDS_AS void*)(&As[(w * 4 + q) * 512]), 16, 0, 0);
      __builtin_amdgcn_global_load_lds(
          (const GLOBAL_AS void*)(gb + (size_t)q * 8 * ld),
          (LDS_AS void*)(&Bs[(w * 4 + q) * 512]), 16, 0, 0);
    }
    ga += 64; gb += 64;
    __syncthreads();
    #pragma unroll
    for (int ks = 0; ks < 2; ++ks) {
      bf16x8 af[4], bfr[4];
      #pragma unroll
      for (int i = 0; i < 4; ++i)
        af[i] = *(const bf16x8*)(&As[(wm + i * 16 + l15) * 64 + ((ks * 4 + quad) ^ sx) * 8]);
      #pragma unroll
      for (int j = 0; j < 4; ++j)
        bfr[j] = *(const bf16x8*)(&Bs[(wn + j * 16 + l15) * 64 + ((ks * 4 + quad) ^ sx) * 8]);
      #pragma unroll
      for (int i = 0; i < 4; ++i)
        #pragma unroll
        for (int j = 0; j < 4; ++j)
          acc[i][j] = __builtin_amdgcn_mfma_f32_16x16x32_bf16(af[i], bfr[j], acc[i][j], 0, 0, 0);
    }
  }

  float* Cz = C + (size_t)z * strideC;
  #pragma unroll
  for (int i = 0; i < 4; ++i) {
    const int rbase = m0 + wm + i * 16 + quad * 4;
    #pragma unroll
    for (int j = 0; j < 4; ++j) {
      const int c = n0 + wn + j * 16 + l15;
      const float badd = (bias && z == 0) ? bias[c] : 0.f;
      #pragma unroll
      for (int r = 0; r < 4; ++r) {
        const int rr = rbase + r;
        float v = acc[i][j][r] + badd;
        if (rr >= mzero) v = 0.f;
        Cz[(size_t)rr * ldc + c] = v;
      }
    }
  }
}

// ---------------------------------------------------------------------------
// 128x64 bf16 MFMA GEMM, split-K over z. MODE 0: f32 partials to C+z*strideC.
// MODE 1: bf16 relu store to Cb (single z). Each wave: 32(M)x64(N).
// ---------------------------------------------------------------------------
template<int MODE>
__global__ __launch_bounds__(256) void gemm_n64(
    const bf16_t* __restrict__ A, const bf16_t* __restrict__ B, int ld,
    float* __restrict__ C, bf16_t* __restrict__ Cb, int ldc, size_t strideC,
    int Ksplit)
{
  __shared__ bf16_t As[128 * 64];
  __shared__ bf16_t Bs[64 * 64];
  const int tid = threadIdx.x;
  const int n0 = blockIdx.x * 64, m0 = blockIdx.y * 128;
  const int z = blockIdx.z;
  const int koff = z * Ksplit;

  const int w = tid >> 6, lane = tid & 63;
  const int srow = lane >> 3;
  const int sblk = (lane & 7) ^ srow;
  const bf16_t* ga = A + (size_t)(m0 + w * 32 + srow) * ld + koff + sblk * 8;
  const bf16_t* gb = B + (size_t)(n0 + w * 16 + srow) * ld + koff + sblk * 8;

  const int l15 = lane & 15, quad = lane >> 4;
  const int sx = l15 & 7;

  floatx4 acc[2][4] = {};

  for (int k0 = 0; k0 < Ksplit; k0 += 64) {
    __syncthreads();
    #pragma unroll
    for (int q = 0; q < 4; ++q)
      __builtin_amdgcn_global_load_lds(
          (const GLOBAL_AS void*)(ga + (size_t)q * 8 * ld),
          (LDS_AS void*)(&As[(w * 4 + q) * 512]), 16, 0, 0);
    #pragma unroll
    for (int q = 0; q < 2; ++q)
      __builtin_amdgcn_global_load_lds(
          (const GLOBAL_AS void*)(gb + (size_t)q * 8 * ld),
          (LDS_AS void*)(&Bs[(w * 2 + q) * 512]), 16, 0, 0);
    ga += 64; gb += 64;
    __syncthreads();
    #pragma unroll
    for (int ks = 0; ks < 2; ++ks) {
      bf16x8 af[2], bfr[4];
      #pragma unroll
      for (int i = 0; i < 2; ++i)
        af[i] = *(const bf16x8*)(&As[(w * 32 + i * 16 + l15) * 64 + ((ks * 4 + quad) ^ sx) * 8]);
      #pragma unroll
      for (int j = 0; j < 4; ++j)
        bfr[j] = *(const bf16x8*)(&Bs[(j * 16 + l15) * 64 + ((ks * 4 + quad) ^ sx) * 8]);
      #pragma unroll
      for (int i = 0; i < 2; ++i)
        #pragma unroll
        for (int j = 0; j < 4; ++j)
          acc[i][j] = __builtin_amdgcn_mfma_f32_16x16x32_bf16(af[i], bfr[j], acc[i][j], 0, 0, 0);
    }
  }

  #pragma unroll
  for (int i = 0; i < 2; ++i) {
    const int rbase = m0 + w * 32 + i * 16 + quad * 4;
    #pragma unroll
    for (int j = 0; j < 4; ++j) {
      const int c = n0 + j * 16 + l15;
      #pragma unroll
      for (int r = 0; r < 4; ++r) {
        const int rr = rbase + r;
        if (MODE == 0)
          (C + (size_t)z * strideC)[(size_t)rr * ldc + c] = acc[i][j][r];
        else
          Cb[(size_t)rr * ldc + c] = (bf16_t)fmaxf(acc[i][j][r], 0.f);
      }
    }
  }
}

// ---------------------------------------------------------------------------
// Prep: f32->bf16 of x-slice, [Wk;Wv], [WEk;WEv], Wout; concat biases.
// grid 3084 x 256.
// ---------------------------------------------------------------------------
__global__ __launch_bounds__(256) void kPrep(
    const float* __restrict__ x, const float* __restrict__ Wk,
    const float* __restrict__ Wv, const float* __restrict__ WEk,
    const float* __restrict__ WEv, const float* __restrict__ bk,
    const float* __restrict__ bv, const float* __restrict__ bEk,
    const float* __restrict__ bEv, const float* __restrict__ Wout,
    bf16_t* __restrict__ xb, bf16_t* __restrict__ Wkvb, bf16_t* __restrict__ WEb,
    bf16_t* __restrict__ Woutb, float* __restrict__ bkv, float* __restrict__ bE)
{
  const int blk = blockIdx.x;
  if (blk == 3072) {
    for (int i = threadIdx.x; i < CH_; i += 256) {
      bkv[i] = bk[i]; bkv[CH_ + i] = bv[i];
      bE[i]  = bEk[i]; bE[CH_ + i] = bEv[i];
    }
    return;
  }
  if (blk > 3072) {
    const size_t e0 = ((size_t)(blk - 3073) * 256 + threadIdx.x) * 16;
    if (e0 < (size_t)NCLS_ * 2 * CH_) {
      #pragma unroll
      for (int q = 0; q < 4; ++q) {
        const float4 v = *(const float4*)(Wout + e0 + q * 4);
        bf16x4 o = { (bf16_t)v.x, (bf16_t)v.y, (bf16_t)v.z, (bf16_t)v.w };
        *(bf16x4*)(Woutb + e0 + q * 4) = o;
      }
    }
    return;
  }
  const int sec = blk >> 10;
  const int t = ((blk & 1023) << 8) + threadIdx.x;
  const size_t e0 = (size_t)t * 16;
  const int row = (int)(e0 >> 11);
  const int col = (int)(e0 & 2047);
  const float* src;
  bf16_t* dst;
  if (sec == 0) {
    src = x + (size_t)row * (T_ * CIN_) + (size_t)(T_ - 1) * CIN_ + col;
    dst = xb + e0;
  } else if (sec == 1) {
    src = (row < CH_ ? Wk + (size_t)row * CIN_ : Wv + (size_t)(row - CH_) * CIN_) + col;
    dst = Wkvb + e0;
  } else {
    src = (row < CH_ ? WEk + (size_t)row * CIN_ : WEv + (size_t)(row - CH_) * CIN_) + col;
    dst = WEb + e0;
  }
  #pragma unroll
  for (int q = 0; q < 4; ++q) {
    const float4 v = *(const float4*)(src + q * 4);
    bf16x4 o = { (bf16_t)v.x, (bf16_t)v.y, (bf16_t)v.z, (bf16_t)v.w };
    *(bf16x4*)(dst + q * 4) = o;
  }
}

// ---------------------------------------------------------------------------
// sf[n][c][m] -> sfTb[n*32+m][c] (bf16), rows 672..767 zero. grid (24,64)x256
// ---------------------------------------------------------------------------
__global__ __launch_bounds__(256) void kTrSf(
    const float* __restrict__ sf, bf16_t* __restrict__ sfTb)
{
  __shared__ float t[32][33];
  const int nn = blockIdx.x;
  const int c0 = blockIdx.y * 32;
  const int tid = threadIdx.x;
  const int cc = tid & 31, r8 = tid >> 5;
  #pragma unroll
  for (int q = 0; q < 4; ++q) {
    const int cl = r8 + q * 8;
    float v = 0.f;
    if (nn < NCLS_) v = sf[((size_t)nn * CIN_ + c0 + cl) * M_ + cc];
    t[cl][cc] = v;
  }
  __syncthreads();
  #pragma unroll
  for (int q = 0; q < 4; ++q) {
    const int ml = r8 + q * 8;
    sfTb[(size_t)(nn * 32 + ml) * CIN_ + c0 + cc] = (bf16_t)t[cc][ml];
  }
}

// ---------------------------------------------------------------------------
// Row r of KVE = KVE0+KVE1. Normalize cols 0..1023 -> knb (r<2048) or Eknb;
// r>=2048 also EvW[r-2048] = dot(cols 1024.., Ww). grid 2816, block 64.
// ---------------------------------------------------------------------------
__global__ __launch_bounds__(64) void kNormKE(
    const float* __restrict__ KVE0, const float* __restrict__ KVE1,
    const float* __restrict__ Ww,
    bf16_t* __restrict__ knb, bf16_t* __restrict__ Eknb, float* __restrict__ EvW)
{
  const int r = blockIdx.x;
  const int lane = threadIdx.x;
  const float* r0 = KVE0 + (size_t)r * 2048;
  const float* r1 = KVE1 + (size_t)r * 2048;
  float vals[16];
  float ss = 0.f;
  #pragma unroll
  for (int i = 0; i < 16; ++i) {
    const int o = lane + i * 64;
    const float v = r0[o] + r1[o];
    vals[i] = v;
    ss += v * v;
  }
  for (int off = 32; off; off >>= 1) ss += __shfl_xor(ss, off);
  const float inv = 1.f / fmaxf(sqrtf(ss), EPS_);
  bf16_t* dst = (r < B_) ? knb + (size_t)r * CH_ : Eknb + (size_t)(r - B_) * CH_;
  #pragma unroll
  for (int i = 0; i < 16; ++i) dst[lane + i * 64] = (bf16_t)(vals[i] * inv);
  if (r >= B_) {
    float dd = 0.f;
    for (int o = lane; o < CH_; o += 64)
      dd += (r0[CH_ + o] + r1[CH_ + o]) * Ww[o];
    for (int off = 32; off; off >>= 1) dd += __shfl_xor(dd, off);
    if (lane == 0) EvW[r - B_] = dd;
  }
}

// ---------------------------------------------------------------------------
// Ev2b[o][nm] = sum_z KVE_z[2048+nm][1024+o] (bf16). grid (24,32) x 256
// ---------------------------------------------------------------------------
__global__ __launch_bounds__(256) void kTrEv(
    const float* __restrict__ KVE0, const float* __restrict__ KVE1,
    bf16_t* __restrict__ Ev2b)
{
  __shared__ float t[32][33];
  const int nm0 = blockIdx.x * 32;
  const int o0 = blockIdx.y * 32;
  const int tid = threadIdx.x;
  const int cc = tid & 31, r8 = tid >> 5;
  #pragma unroll
  for (int q = 0; q < 4; ++q) {
    const int r = r8 + q * 8;
    const size_t idx = (size_t)(B_ + nm0 + r) * 2048 + CH_ + o0 + cc;
    t[r][cc] = KVE0[idx] + KVE1[idx];
  }
  __syncthreads();
  #pragma unroll
  for (int q = 0; q < 4; ++q) {
    const int r = r8 + q * 8;
    Ev2b[(size_t)(o0 + r) * NMP_ + nm0 + cc] = (bf16_t)t[cc][r];
  }
}

// ---------------------------------------------------------------------------
// Softmax chain per b, summing split-K cos planes. -> wwb bf16, pads zero.
// ---------------------------------------------------------------------------
__global__ __launch_bounds__(256) void kSoftmax(
    const float* __restrict__ cosb0, const float* __restrict__ cosb1,
    const float* __restrict__ EvW, const float* __restrict__ bw,
    bf16_t* __restrict__ wwb)
{
  const int b = blockIdx.x;
  const int tid = threadIdx.x;
  __shared__ float sc[NM_];
  __shared__ float sl[NCLS_];
  for (int i = tid; i < NM_; i += 256)
    sc[i] = cosb0[(size_t)b * NMP_ + i] + cosb1[(size_t)b * NMP_ + i];
  __syncthreads();
  if (tid < NCLS_) {
    const int base = tid * M_;
    float mx = -1e30f;
    for (int m = 0; m < M_; ++m) mx = fmaxf(mx, sc[base + m]);
    float s = 0.f;
    for (int m = 0; m < M_; ++m) {
      const float e = __expf(sc[base + m] - mx);
      sc[base + m] = e;
      s += e;
    }
    const float inv = 1.f / s;
    float lg = 0.f;
    for (int m = 0; m < M_; ++m) {
      const float w = sc[base + m] * inv;
      sc[base + m] = w;
      lg += w * EvW[base + m];
    }
    sl[tid] = lg + bw[0];
  }
  __syncthreads();
  if (tid == 0) {
    float mx = -1e30f;
    for (int n = 0; n < NCLS_; ++n) mx = fmaxf(mx, sl[n]);
    float s = 0.f;
    for (int n = 0; n < NCLS_; ++n) { const float e = __expf(sl[n] - mx); sl[n] = e; s += e; }
    const float inv = 1.f / s;
    for (int n = 0; n < NCLS_; ++n) sl[n] *= inv;
  }
  __syncthreads();
  for (int i = tid; i < NMP_; i += 256) {
    const float v = (i < NM_) ? sc[i] * sl[i >> 5] : 0.f;
    wwb[(size_t)b * NMP_ + i] = (bf16_t)v;
  }
}

// ---------------------------------------------------------------------------
// out[b,n] = bout[n] + sum_j relu(h[j]) * Woutb[n,j]; h = [v0+v1, fEb(relu'd)]
// ---------------------------------------------------------------------------
__global__ __launch_bounds__(256) void kOut(
    const float* __restrict__ KVE0, const float* __restrict__ KVE1,
    const bf16_t* __restrict__ fEb, const bf16_t* __restrict__ Woutb,
    const float* __restrict__ bout, float* __restrict__ out)
{
  const int b = blockIdx.x;
  const int tid = threadIdx.x;
  __shared__ float h[2 * CH_];
  for (int j = tid; j < CH_; j += 256) {
    const size_t idx = (size_t)b * 2048 + CH_ + j;
    h[j] = fmaxf(KVE0[idx] + KVE1[idx], 0.f);
  }
  for (int j = tid; j < CH_; j += 256)
    h[CH_ + j] = (float)fEb[(size_t)b * CH_ + j];
  __syncthreads();
  const int wave = tid >> 6, lane = tid & 63;
  for (int n = wave; n < NCLS_; n += 4) {
    const bf16_t* wr = Woutb + (size_t)n * (2 * CH_);
    float s = 0.f;
    for (int j = lane; j < 2 * CH_; j += 64) s += h[j] * (float)wr[j];
    for (int off = 32; off; off >>= 1) s += __shfl_xor(s, off);
    if (lane == 0) out[(size_t)b * NCLS_ + n] = s + bout[n];
  }
}

// ---------------------------------------------------------------------------
extern "C" void kernel_launch(void* const* d_in, const int* in_sizes, int n_in,
                              void* d_out, int out_size, void* d_ws, size_t ws_size,
                              hipStream_t stream)
{
  const float* x    = (const float*)d_in[0];
  const float* sf   = (const float*)d_in[1];
  const float* Wk   = (const float*)d_in[2];
  const float* bk   = (const float*)d_in[3];
  const float* Wv   = (const float*)d_in[4];
  const float* bv   = (const float*)d_in[5];
  const float* WEk  = (const float*)d_in[6];
  const float* bEk  = (const float*)d_in[7];
  const float* WEv  = (const float*)d_in[8];
  const float* bEv  = (const float*)d_in[9];
  const float* Ww   = (const float*)d_in[10];
  const float* bw   = (const float*)d_in[11];
  const float* Wout = (const float*)d_in[12];
  const float* bout = (const float*)d_in[13];
  float* out = (float*)d_out;

  char* ws = (char*)d_ws;
  size_t off = 0;
  auto alloc = [&](size_t bytes) { char* p = ws + off; off += (bytes + 255) & ~(size_t)255; return p; };
  float*  KVE0  = (float*)alloc((size_t)2816 * 2048 * 4);   // 23.07 MB
  float*  KVE1  = (float*)alloc((size_t)2816 * 2048 * 4);   // 23.07 MB
  bf16_t* xb    = (bf16_t*)alloc((size_t)2048 * 2048 * 2);  //  8.39 MB
  bf16_t* Wkvb  = (bf16_t*)alloc((size_t)2048 * 2048 * 2);
  bf16_t* WEb   = (bf16_t*)alloc((size_t)2048 * 2048 * 2);
  bf16_t* sfTb  = (bf16_t*)alloc((size_t)NMP_ * 2048 * 2);  //  3.15 MB
  bf16_t* knb   = (bf16_t*)alloc((size_t)B_ * CH_ * 2);     //  4.19 MB
  bf16_t* Eknb  = (bf16_t*)alloc((size_t)NMP_ * CH_ * 2);   //  1.57 MB
  bf16_t* Ev2b  = (bf16_t*)alloc((size_t)CH_ * NMP_ * 2);   //  1.57 MB
  float*  cosb0 = (float*)alloc((size_t)B_ * NMP_ * 4);     //  6.29 MB
  float*  cosb1 = (float*)alloc((size_t)B_ * NMP_ * 4);
  bf16_t* wwb   = (bf16_t*)alloc((size_t)B_ * NMP_ * 2);    //  3.15 MB
  bf16_t* fEb   = (bf16_t*)alloc((size_t)B_ * CH_ * 2);     //  4.19 MB
  bf16_t* Woutb = (bf16_t*)alloc((size_t)NCLS_ * 2 * CH_ * 2);
  float*  bkv   = (float*)alloc(2 * CH_ * 4);
  float*  bE    = (float*)alloc(2 * CH_ * 4);
  float*  EvW   = (float*)alloc(NMP_ * 4);

  // 1) conversions
  kPrep<<<3084, 256, 0, stream>>>(x, Wk, Wv, WEk, WEv, bk, bv, bEk, bEv, Wout,
                                  xb, Wkvb, WEb, Woutb, bkv, bE);
  kTrSf<<<dim3(24, CIN_ / 32), 256, 0, stream>>>(sf, sfTb);
  // 2) fused kv+E GEMM, split-K x2 (704 blocks), partials KVE0/KVE1
  gemm128<<<dim3(16, 22, 2), 256, 0, stream>>>(
      xb, sfTb, B_, Wkvb, WEb, bkv, bE, CIN_,
      KVE0, 2048, (size_t)(KVE1 - KVE0), B_ + NM_, CIN_ / 2);
  // 3) sum + normalize -> knb/Eknb, EvW
  kNormKE<<<B_ + NMP_, 64, 0, stream>>>(KVE0, KVE1, Ww, knb, Eknb, EvW);
  // 4) Ev transpose -> Ev2b
  kTrEv<<<dim3(NMP_ / 32, CH_ / 32), 256, 0, stream>>>(KVE0, KVE1, Ev2b);
  // 5) cos GEMM, 128x64 tiles, split-K x2 (384 blocks)
  gemm_n64<0><<<dim3(NMP_ / 64, 16, 2), 256, 0, stream>>>(
      knb, Eknb, CH_, cosb0, nullptr, NMP_, (size_t)(cosb1 - cosb0), CH_ / 2);
  // 6) softmax chain -> wwb
  kSoftmax<<<B_, 256, 0, stream>>>(cosb0, cosb1, EvW, bw, wwb);
  // 7) fE GEMM, 128x64 tiles (256 blocks), relu-bf16 epilogue
  gemm_n64<1><<<dim3(CH_ / 64, 16, 1), 256, 0, stream>>>(
      wwb, Ev2b, NMP_, nullptr, fEb, CH_, 0, NMP_);
  // 8) output
  kOut<<<B_, 256, 0, stream>>>(KVE0, KVE1, fEb, Woutb, bout, out);
}